// Round 1
// baseline (644.255 us; speedup 1.0000x reference)
//
#include <hip/hip_runtime.h>

#define N_ 32
#define C_ 64
#define H_ 128
#define W_ 128
#define HW_ (H_ * W_)
#define CHW_ (C_ * HW_)
#define LDS_STRIDE 152  // 13 front pad + 128 + 11 back pad

// Transpose conv weights: Wt[(i*7 + t)*64 + o] = Wc[o*448 + i*7 + t]
__global__ void wt_transpose_kernel(const float* __restrict__ Wc, float* __restrict__ Wt) {
    int idx = blockIdx.x * 256 + threadIdx.x;
    if (idx >= C_ * C_ * 7) return;
    int o = idx / 448;
    int r = idx % 448;
    int i = r / 7;
    int t = r % 7;
    Wt[(i * 7 + t) * 64 + o] = Wc[idx];
}

__global__ __launch_bounds__(256) void fused_conv_roll_kernel(
    const float* __restrict__ x, const float* __restrict__ Wt,
    const float* __restrict__ p4w, float* __restrict__ out)
{
    __shared__ float xs[C_ * LDS_STRIDE];  // 64 * 152 * 4 = 38912 B

    const int nb = blockIdx.x;   // 0..4095
    const int n = nb >> 7;
    const int h = nb & 127;
    const int tid = threadIdx.x;
    const float* xn = x + (size_t)n * CHW_;

    // ---- Stage x slice (row h, all 64 channels) into LDS, coalesced float4 ----
    // 64*128 floats = 2048 float4; 256 threads -> 8 iters
    for (int k = 0; k < 8; ++k) {
        int f4 = k * 256 + tid;          // 0..2047
        int c = f4 >> 5;                 // 32 float4 per channel row
        int w4 = f4 & 31;
        float4 v = *(const float4*)(xn + c * HW_ + h * W_ + w4 * 4);
        float* dst = &xs[c * LDS_STRIDE + w4 * 4 + 13];
        dst[0] = v.x; dst[1] = v.y; dst[2] = v.z; dst[3] = v.w;
    }
    // ---- Zero pads: 13 front + 11 back per row = 24 * 64 = 1536 ----
    for (int f = tid; f < C_ * 24; f += 256) {
        int c = f / 24, p = f % 24;
        int col = (p < 13) ? p : (128 + p);   // p=13 -> col 141 ... p=23 -> col 151
        xs[c * LDS_STRIDE + col] = 0.f;
    }
    __syncthreads();

    // ---- Lane mapping: o per lane (wave-uniform LDS window), w-chunk per wave ----
    const int o = tid & 63;
    const int w0 = (tid >> 6) * 32;   // 0,32,64,96

    float acc[32];
    #pragma unroll
    for (int j = 0; j < 32; ++j) acc[j] = 0.f;

    for (int i = 0; i < C_; ++i) {
        // window xw[m] = x[i][w0 + m - 9] (zero padded), m = j + 3t, m in [0,49]
        float xw[52];
        const float4* src = (const float4*)(xs + i * LDS_STRIDE + w0 + 4);
        #pragma unroll
        for (int k = 0; k < 13; ++k) {
            float4 v = src[k];
            xw[4 * k + 0] = v.x; xw[4 * k + 1] = v.y;
            xw[4 * k + 2] = v.z; xw[4 * k + 3] = v.w;
        }
        const float* wp = Wt + i * 448 + o;   // Wt[(i*7+t)*64 + o]
        float wv[7];
        #pragma unroll
        for (int t = 0; t < 7; ++t) wv[t] = wp[t * 64];
        #pragma unroll
        for (int t = 0; t < 7; ++t) {
            #pragma unroll
            for (int j = 0; j < 32; ++j) {
                acc[j] = fmaf(wv[t], xw[j + 3 * t], acc[j]);
            }
        }
    }

    // ---- Epilogue: t4 (unfold-roll-reduce) and final fuse ----
    const float p0 = p4w[0], p1 = p4w[1], p2 = p4w[2];
    const int h1 = (h - 1 + H_) & 127;       // roll +1 along h
    const float* xc = xn + o * HW_;
    float* outp = out + (size_t)n * CHW_ + o * HW_ + h * W_;

    #pragma unroll
    for (int jc = 0; jc < 8; ++jc) {
        int w = w0 + jc * 4;
        int wsrc = w + 2;                    // roll -2 along w: source col (w+2) % 128
        float tap[3][4];
        #pragma unroll
        for (int k = 0; k < 3; ++k) {
            int hh = h1 + 2 * k - 2;         // unfold taps: h1-2, h1, h1+2 (zero outside)
            if (hh >= 0 && hh < H_) {
                const float* rowp = xc + hh * W_;
                float2 a = *(const float2*)(rowp + wsrc);                  // wsrc <= 126, even
                float2 b = *(const float2*)(rowp + ((wsrc + 2) & 127));    // handles wrap at 128
                tap[k][0] = a.x; tap[k][1] = a.y; tap[k][2] = b.x; tap[k][3] = b.y;
            } else {
                tap[k][0] = tap[k][1] = tap[k][2] = tap[k][3] = 0.f;
            }
        }
        float ovv[4];
        #pragma unroll
        for (int e = 0; e < 4; ++e) {
            float t4 = p0 * tap[0][e] + p1 * tap[1][e] + p2 * tap[2][e];
            float xv = xs[o * LDS_STRIDE + w + 13 + e];
            ovv[e] = (xv + acc[jc * 4 + e]) * t4;
        }
        *(float4*)(outp + w) = make_float4(ovv[0], ovv[1], ovv[2], ovv[3]);
    }
}

extern "C" void kernel_launch(void* const* d_in, const int* in_sizes, int n_in,
                              void* d_out, int out_size, void* d_ws, size_t ws_size,
                              hipStream_t stream) {
    const float* x     = (const float*)d_in[0];
    const float* Wc    = (const float*)d_in[1];
    const float* p4w   = (const float*)d_in[2];
    float* out         = (float*)d_out;
    float* Wt          = (float*)d_ws;   // 64*64*7 floats = 114688 B

    wt_transpose_kernel<<<(C_ * C_ * 7 + 255) / 256, 256, 0, stream>>>(Wc, Wt);
    fused_conv_roll_kernel<<<N_ * H_, 256, 0, stream>>>(x, Wt, p4w, out);
}

// Round 2
// 285.660 us; speedup vs baseline: 2.2553x; 2.2553x over previous
//
#include <hip/hip_runtime.h>
#include <hip/hip_bf16.h>

#define N_ 32
#define C_ 64
#define H_ 128
#define W_ 128
#define HW_ (H_ * W_)
#define CHW_ (C_ * HW_)

#define XT_STRIDE 68           // halfs per row; row = w+9 (146 rows), col = channel
#define XT_ROWS 146
#define CB_STRIDE 130          // floats per conv-buffer row (16 rows per wave)

typedef __bf16 bf16x8 __attribute__((ext_vector_type(8)));
typedef float floatx4 __attribute__((ext_vector_type(4)));

__device__ inline unsigned short f2bf(float f) {
    __hip_bfloat16 h = __float2bfloat16(f);
    return *reinterpret_cast<unsigned short*>(&h);
}

// Pre-pack weights into MFMA A-fragment order (bf16).
// A[o][k], k = t*64 + i, from Wc[o*448 + i*7 + t].
// Apack[(kt*4 + mt)*64 + lane] = uint4 of 8 bf16:
//   lane: m = mt*16 + (lane&15), k = kt*32 + (lane>>4)*8 + j, j=0..7
__global__ void prepack_kernel(const float* __restrict__ Wc, uint4* __restrict__ Ap) {
    int idx = blockIdx.x * 256 + threadIdx.x;
    if (idx >= 14 * 4 * 64) return;
    int lane = idx & 63;
    int mt = (idx >> 6) & 3;
    int kt = idx >> 8;
    int m = mt * 16 + (lane & 15);
    int kbase = kt * 32 + (lane >> 4) * 8;
    unsigned int r[4];
    #pragma unroll
    for (int p = 0; p < 4; ++p) {
        unsigned int half[2];
        #pragma unroll
        for (int jj = 0; jj < 2; ++jj) {
            int k = kbase + 2 * p + jj;
            int t = k >> 6;
            int i = k & 63;
            half[jj] = f2bf(Wc[m * 448 + i * 7 + t]);
        }
        r[p] = half[0] | (half[1] << 16);
    }
    Ap[idx] = make_uint4(r[0], r[1], r[2], r[3]);
}

__global__ __launch_bounds__(256) void fused_mfma_kernel(
    const float* __restrict__ x, const uint4* __restrict__ Ap,
    const float* __restrict__ p4w, float* __restrict__ out)
{
    __shared__ unsigned short xT[XT_ROWS * XT_STRIDE];   // 19856 B
    __shared__ float convbuf[4 * 16 * CB_STRIDE];        // 33280 B

    const int nb = blockIdx.x;
    const int n = nb >> 7;
    const int h = nb & 127;
    const int tid = threadIdx.x;
    const int wave = tid >> 6;
    const int lane = tid & 63;
    const int l16 = lane & 15;
    const int quad = lane >> 4;
    const float* xn = x + (size_t)n * CHW_;

    // ---- zero the pad rows (rows 0..8 and 137..145), dword writes ----
    unsigned int* xz = (unsigned int*)xT;
    for (int i = tid; i < 612; i += 256) {
        int d = (i < 306) ? i : (4658 + (i - 306));   // 137*34 = 4658
        xz[d] = 0u;
    }

    // ---- stage x row-h slice into xT (transposed, bf16) ----
    const float* xrow = xn + h * W_;
    #pragma unroll
    for (int k = 0; k < 8; ++k) {
        int f4 = k * 256 + tid;
        int c = f4 >> 5;
        int w4 = f4 & 31;
        float4 v = *(const float4*)(xrow + c * HW_ + w4 * 4);
        int w = w4 * 4;
        xT[(w + 9) * XT_STRIDE + c]  = f2bf(v.x);
        xT[(w + 10) * XT_STRIDE + c] = f2bf(v.y);
        xT[(w + 11) * XT_STRIDE + c] = f2bf(v.z);
        xT[(w + 12) * XT_STRIDE + c] = f2bf(v.w);
    }

    // ---- load this wave's 14 A fragments (m-tile = wave) ----
    uint4 afrag[14];
    #pragma unroll
    for (int kt = 0; kt < 14; ++kt)
        afrag[kt] = Ap[kt * 256 + wave * 64 + lane];

    __syncthreads();

    // ---- MFMA K-loop: O[o0+16][128] for o0 = wave*16 ----
    floatx4 acc[8];
    #pragma unroll
    for (int nt = 0; nt < 8; ++nt) acc[nt] = (floatx4){0.f, 0.f, 0.f, 0.f};

    const int base_half = l16 * XT_STRIDE + quad * 8;
    #pragma unroll
    for (int kt = 0; kt < 14; ++kt) {
        bf16x8 av = __builtin_bit_cast(bf16x8, afrag[kt]);
        int koff = (kt >> 1) * 3 * XT_STRIDE + (kt & 1) * 32;
        #pragma unroll
        for (int nt = 0; nt < 8; ++nt) {
            int off = base_half + koff + nt * 16 * XT_STRIDE;
            uint2 d0 = *(const uint2*)&xT[off];
            uint2 d1 = *(const uint2*)&xT[off + 4];
            bf16x8 bv = __builtin_bit_cast(bf16x8, make_uint4(d0.x, d0.y, d1.x, d1.y));
            acc[nt] = __builtin_amdgcn_mfma_f32_16x16x32_bf16(av, bv, acc[nt], 0, 0, 0);
        }
    }

    // ---- round-trip conv result through LDS (wave-private area) ----
    float* cw = convbuf + wave * 16 * CB_STRIDE;
    #pragma unroll
    for (int nt = 0; nt < 8; ++nt) {
        #pragma unroll
        for (int r = 0; r < 4; ++r)
            cw[(quad * 4 + r) * CB_STRIDE + nt * 16 + l16] = acc[nt][r];
    }

    // ---- epilogue: t4 + fuse + coalesced float4 stores ----
    const float p0 = p4w[0], p1 = p4w[1], p2 = p4w[2];
    const int h1 = (h - 1 + H_) & 127;

    #pragma unroll
    for (int j = 0; j < 8; ++j) {
        int idx = j * 64 + lane;           // 0..511
        int o_ = idx >> 5;                 // 0..15
        int w4 = idx & 31;
        int w = w4 * 4;
        int o = wave * 16 + o_;

        float4 cv = *(const float4*)&cw[o_ * CB_STRIDE + w];

        const float* xc = xn + o * HW_;
        float4 xv = *(const float4*)(xc + h * W_ + w);

        int wsrc = w + 2;
        float tap[3][4];
        #pragma unroll
        for (int k = 0; k < 3; ++k) {
            int hh = h1 + 2 * k - 2;
            if (hh >= 0 && hh < H_) {
                const float* rowp = xc + hh * W_;
                float2 a = *(const float2*)(rowp + wsrc);
                float2 b = *(const float2*)(rowp + ((wsrc + 2) & 127));
                tap[k][0] = a.x; tap[k][1] = a.y; tap[k][2] = b.x; tap[k][3] = b.y;
            } else {
                tap[k][0] = tap[k][1] = tap[k][2] = tap[k][3] = 0.f;
            }
        }
        float ov[4];
        float xa[4] = {xv.x, xv.y, xv.z, xv.w};
        float ca[4] = {cv.x, cv.y, cv.z, cv.w};
        #pragma unroll
        for (int e = 0; e < 4; ++e) {
            float t4 = p0 * tap[0][e] + p1 * tap[1][e] + p2 * tap[2][e];
            ov[e] = (xa[e] + ca[e]) * t4;
        }
        *(float4*)(out + (size_t)n * CHW_ + o * HW_ + h * W_ + w) =
            make_float4(ov[0], ov[1], ov[2], ov[3]);
    }
}

extern "C" void kernel_launch(void* const* d_in, const int* in_sizes, int n_in,
                              void* d_out, int out_size, void* d_ws, size_t ws_size,
                              hipStream_t stream) {
    const float* x   = (const float*)d_in[0];
    const float* Wc  = (const float*)d_in[1];
    const float* p4w = (const float*)d_in[2];
    float* out       = (float*)d_out;
    uint4* Apack     = (uint4*)d_ws;   // 14*4*64*16 = 57344 B

    prepack_kernel<<<14, 256, 0, stream>>>(Wc, Apack);
    fused_mfma_kernel<<<N_ * H_, 256, 0, stream>>>(x, Apack, p4w, out);
}

// Round 3
// 272.874 us; speedup vs baseline: 2.3610x; 1.0469x over previous
//
#include <hip/hip_runtime.h>
#include <hip/hip_bf16.h>

#define N_ 32
#define C_ 64
#define H_ 128
#define W_ 128
#define HW_ (H_ * W_)
#define CHW_ (C_ * HW_)

#define XT_STRIDE 72           // halfs per row (144 B, 16B-aligned); row = w+9, col = channel
#define XT_ROWS 146
#define CB_STRIDE 130          // floats per conv-buffer row (16 rows per wave)
#define SMEM_BYTES (4 * 16 * CB_STRIDE * 4)   // 33280 >= 146*72*2 = 21024

typedef __bf16 bf16x8 __attribute__((ext_vector_type(8)));
typedef float floatx4 __attribute__((ext_vector_type(4)));

__device__ inline unsigned short f2bf(float f) {
    __hip_bfloat16 h = __float2bfloat16(f);
    return *reinterpret_cast<unsigned short*>(&h);
}

// Pre-pack weights into MFMA A-fragment order (bf16).
// A[o][k], k = t*64 + i, from Wc[o*448 + i*7 + t].
__global__ void prepack_kernel(const float* __restrict__ Wc, uint4* __restrict__ Ap) {
    int idx = blockIdx.x * 256 + threadIdx.x;
    if (idx >= 14 * 4 * 64) return;
    int lane = idx & 63;
    int mt = (idx >> 6) & 3;
    int kt = idx >> 8;
    int m = mt * 16 + (lane & 15);
    int kbase = kt * 32 + (lane >> 4) * 8;
    unsigned int r[4];
    #pragma unroll
    for (int p = 0; p < 4; ++p) {
        unsigned int half[2];
        #pragma unroll
        for (int jj = 0; jj < 2; ++jj) {
            int k = kbase + 2 * p + jj;
            int t = k >> 6;
            int i = k & 63;
            half[jj] = f2bf(Wc[m * 448 + i * 7 + t]);
        }
        r[p] = half[0] | (half[1] << 16);
    }
    Ap[idx] = make_uint4(r[0], r[1], r[2], r[3]);
}

__global__ __launch_bounds__(256) void fused_mfma_kernel(
    const float* __restrict__ x, const uint4* __restrict__ Ap,
    const float* __restrict__ p4w, float* __restrict__ out)
{
    // xT (bf16 staging, 21 KB) and convbuf (fp32, 33 KB) are never live
    // simultaneously: union them. LDS 33280 B -> 4 blocks/CU.
    __shared__ __attribute__((aligned(16))) char smem[SMEM_BYTES];
    unsigned short* xT = (unsigned short*)smem;
    float* convbuf = (float*)smem;

    // XCD-aware swizzle: xcd = b&7 (round-robin dispatch). Each XCD owns a
    // contiguous 16-row h-chunk per n, so epilogue tap rows (h-3,h-1,h+1)
    // hit the home XCD's L2 instead of re-fetching from HBM.
    const int b = blockIdx.x;
    const int xcd = b & 7;
    const int i_ = b >> 3;           // 0..511
    const int n = i_ >> 4;           // 0..31
    const int h = xcd * 16 + (i_ & 15);

    const int tid = threadIdx.x;
    const int wave = tid >> 6;
    const int lane = tid & 63;
    const int l16 = lane & 15;
    const int quad = lane >> 4;
    const float* xn = x + (size_t)n * CHW_;

    // ---- zero pad rows (rows 0..8 and 137..145), dword writes ----
    // rows 0..8 = dwords [0,324); rows 137..145 = dwords [4932,5256)
    unsigned int* xz = (unsigned int*)xT;
    for (int i = tid; i < 648; i += 256) {
        int d = (i < 324) ? i : (4932 + (i - 324));
        xz[d] = 0u;
    }

    // ---- stage x row-h slice into xT (transposed, bf16) ----
    const float* xrow = xn + h * W_;
    #pragma unroll
    for (int k = 0; k < 8; ++k) {
        int f4 = k * 256 + tid;
        int c = f4 >> 5;
        int w4 = f4 & 31;
        float4 v = *(const float4*)(xrow + c * HW_ + w4 * 4);
        int w = w4 * 4;
        xT[(w + 9) * XT_STRIDE + c]  = f2bf(v.x);
        xT[(w + 10) * XT_STRIDE + c] = f2bf(v.y);
        xT[(w + 11) * XT_STRIDE + c] = f2bf(v.z);
        xT[(w + 12) * XT_STRIDE + c] = f2bf(v.w);
    }

    // ---- load this wave's 14 A fragments (m-tile = wave) ----
    uint4 afrag[14];
    #pragma unroll
    for (int kt = 0; kt < 14; ++kt)
        afrag[kt] = Ap[kt * 256 + wave * 64 + lane];

    __syncthreads();

    // ---- MFMA K-loop: O[o0+16][128] for o0 = wave*16 ----
    floatx4 acc[8];
    #pragma unroll
    for (int nt = 0; nt < 8; ++nt) acc[nt] = (floatx4){0.f, 0.f, 0.f, 0.f};

    const int base_half = l16 * XT_STRIDE + quad * 8;
    #pragma unroll
    for (int kt = 0; kt < 14; ++kt) {
        bf16x8 av = __builtin_bit_cast(bf16x8, afrag[kt]);
        int koff = (kt >> 1) * 3 * XT_STRIDE + (kt & 1) * 32;
        #pragma unroll
        for (int nt = 0; nt < 8; ++nt) {
            int off = base_half + koff + nt * 16 * XT_STRIDE;
            uint4 d = *(const uint4*)&xT[off];           // ds_read_b128, 16B-aligned
            bf16x8 bv = __builtin_bit_cast(bf16x8, d);
            acc[nt] = __builtin_amdgcn_mfma_f32_16x16x32_bf16(av, bv, acc[nt], 0, 0, 0);
        }
    }

    // xT is dead past here; convbuf aliases it — barrier before reuse.
    __syncthreads();

    // ---- round-trip conv result through LDS (wave-private area) ----
    float* cw = convbuf + wave * 16 * CB_STRIDE;
    #pragma unroll
    for (int nt = 0; nt < 8; ++nt) {
        #pragma unroll
        for (int r = 0; r < 4; ++r)
            cw[(quad * 4 + r) * CB_STRIDE + nt * 16 + l16] = acc[nt][r];
    }

    // ---- epilogue: t4 + fuse + coalesced float4 stores ----
    const float p0 = p4w[0], p1 = p4w[1], p2 = p4w[2];
    const int h1 = (h - 1 + H_) & 127;

    #pragma unroll
    for (int j = 0; j < 8; ++j) {
        int idx = j * 64 + lane;           // 0..511
        int o_ = idx >> 5;                 // 0..15
        int w4 = idx & 31;
        int w = w4 * 4;
        int o = wave * 16 + o_;

        float4 cv = *(const float4*)&cw[o_ * CB_STRIDE + w];

        const float* xc = xn + o * HW_;
        float4 xv = *(const float4*)(xc + h * W_ + w);

        int wsrc = w + 2;
        float tap[3][4];
        #pragma unroll
        for (int k = 0; k < 3; ++k) {
            int hh = h1 + 2 * k - 2;
            if (hh >= 0 && hh < H_) {
                const float* rowp = xc + hh * W_;
                float2 a = *(const float2*)(rowp + wsrc);
                float2 b2 = *(const float2*)(rowp + ((wsrc + 2) & 127));
                tap[k][0] = a.x; tap[k][1] = a.y; tap[k][2] = b2.x; tap[k][3] = b2.y;
            } else {
                tap[k][0] = tap[k][1] = tap[k][2] = tap[k][3] = 0.f;
            }
        }
        float ov[4];
        float xa[4] = {xv.x, xv.y, xv.z, xv.w};
        float ca[4] = {cv.x, cv.y, cv.z, cv.w};
        #pragma unroll
        for (int e = 0; e < 4; ++e) {
            float t4 = p0 * tap[0][e] + p1 * tap[1][e] + p2 * tap[2][e];
            ov[e] = (xa[e] + ca[e]) * t4;
        }
        *(float4*)(out + (size_t)n * CHW_ + o * HW_ + h * W_ + w) =
            make_float4(ov[0], ov[1], ov[2], ov[3]);
    }
}

extern "C" void kernel_launch(void* const* d_in, const int* in_sizes, int n_in,
                              void* d_out, int out_size, void* d_ws, size_t ws_size,
                              hipStream_t stream) {
    const float* x   = (const float*)d_in[0];
    const float* Wc  = (const float*)d_in[1];
    const float* p4w = (const float*)d_in[2];
    float* out       = (float*)d_out;
    uint4* Apack     = (uint4*)d_ws;   // 14*4*64*16 = 57344 B

    prepack_kernel<<<14, 256, 0, stream>>>(Wc, Apack);
    fused_mfma_kernel<<<N_ * H_, 256, 0, stream>>>(x, Apack, p4w, out);
}